// Round 5
// baseline (500.535 us; speedup 1.0000x reference)
//
#include <hip/hip_runtime.h>
#include <hip/hip_bf16.h>

// ---------------------------------------------------------------------------
// DenseCorr2d_full — FUSED corr+merge on MFMA bf16 (round 8, resubmit —
// round 4 bench was an infra failure: "container failed twice", no result).
//
// = round-5 structure (the 194µs fused kernel: 2-parity smT, pitch-72 smC,
//   4x ds_read_b32 corr frags, direct staging) with ONE change: tile is
//   64co x 8y x 16x -> grid 1024 = 4 blocks/CU (was 512 = 2/CU, the 45%
//   occupancy wall). LDS 39.5KB (4x fits 160KB); __launch_bounds__(512,8)
//   caps VGPR at 64 for 8 waves/SIMD. 32 waves/CU doubles latency hiding
//   for a kernel where all pipes measured <46% busy (latency-bound).
// r7's PREF regs dropped (spilled: +6MB WRITE_SIZE scratch tripwire).
// ws layout: Wb bf16 [9][64][256] only.
// ---------------------------------------------------------------------------

typedef __attribute__((ext_vector_type(4))) float  f32x4;
typedef __attribute__((ext_vector_type(8))) short  bf16x8;

__device__ inline unsigned int pack_bf16x2(float a, float b) {
    unsigned int ua = __builtin_bit_cast(unsigned int, a);
    unsigned int ub = __builtin_bit_cast(unsigned int, b);
    ua = (ua + 0x7fffu + ((ua >> 16) & 1u)) >> 16;   // RNE
    ub = (ub + 0x7fffu + ((ub >> 16) & 1u)) >> 16;
    return ua | (ub << 16);
}
__device__ inline unsigned short cvt1(float f) {
    unsigned int u = __builtin_bit_cast(unsigned int, f);
    return (unsigned short)((u + 0x7fffu + ((u >> 16) & 1u)) >> 16);
}

// ---------------- W transform: [co][cin][3][3] fp32 -> Wb[kk][co][256] bf16 -
__global__ __launch_bounds__(256) void wt_kernel(
    const float* __restrict__ W, unsigned short* __restrict__ Wb)
{
    int idx = (int)blockIdx.x * 256 + (int)threadIdx.x;   // < 9*64*256
    int c  = idx & 255;
    int rem = idx >> 8;
    int co = rem % 64;
    int kk = rem / 64;
    Wb[idx] = cvt1(W[(size_t)co * 2304 + (size_t)c * 9 + kk]);
}

// ---------------- Fused corr + 3x3 SAME merge conv --------------------------
__global__ __launch_bounds__(512, 8) void fused_mfma(
    const float* __restrict__ tp, const float* __restrict__ tm,
    const unsigned short* __restrict__ Wb, const float* __restrict__ bias,
    float* __restrict__ out)
{
    // tm halo, 2 parity copies: [cm 4][par 2][row 25][pitch 34] = 13600 B
    // (pitch 17 dwords, odd -> n-lanes spread banks like r5's pitch 41)
    __shared__ __align__(16) unsigned short smT[4 * 2 * 25 * 34];
    // corr slab: [pix 180 = 10r x 18c][72 ch-pitch] = 25920 B
    __shared__ __align__(16) unsigned short smC[180 * 72];

    const int t    = threadIdx.x;
    const int wave = t >> 6, lane = t & 63;
    const int n    = lane & 15, quad = lane >> 4;
    const int qh   = quad >> 1, jq = quad & 1;

    const int x0 = (int)blockIdx.x << 4;   // 0..112
    const int y0 = (int)blockIdx.y << 3;   // 0..120
    const int b  = (int)blockIdx.z;

    f32x4 acc[4];                          // merge accumulators [ct]
#pragma unroll
    for (int a = 0; a < 4; ++a) acc[a] = (f32x4){0.f, 0.f, 0.f, 0.f};

#pragma unroll 1
    for (int s = 0; s < 4; ++s) {
        // ---- 1. stage tm halo for cm = 4s..4s+3: rows y0-1..y0+23,
        //         cols x0-1..x0+31 (edge-clamped), parity-shifted copy ----
        {
            const float* tmb = tm + ((size_t)(b * 16 + (s << 2)) << 14);
#pragma unroll 1
            for (int e = t; e < 3400; e += 512) {     // 4 cm * 25 r * 34 c
                int cm  = e / 850;
                int rem = e - 850 * cm;
                int r   = rem / 34;
                int c   = rem - 34 * r;
                int gy = y0 - 1 + r; gy = gy < 0 ? 0 : (gy > 127 ? 127 : gy);
                int gx = x0 - 1 + c; gx = gx < 0 ? 0 : (gx > 127 ? 127 : gx);
                unsigned short h = cvt1(tmb[((size_t)cm << 14) + (gy << 7) + gx]);
                int a0 = cm * 1700 + r * 34 + c;      // parity-0 plane
                smT[a0] = h;                          // copy1[c-1] = tm[c]
                if (c > 0) smT[a0 + 849] = h;         // +850 plane, -1 col
            }
        }

        // ---- corr A-frags (reloaded per slab; asm defeats LICM so the 32
        //      regs don't stay live across merge). L1-hot after slab 0. ----
        bf16x8 bq[8];
        {
            const float* tpb = tp + (((size_t)(b * 16 + n)) << 8);
            asm volatile("" : "+v"(tpb));
#pragma unroll
            for (int kc = 0; kc < 8; ++kc) {
                const float4* q = (const float4*)(tpb + (((2 * kc + qh) << 4) + (jq << 3)));
                float4 a = q[0], c4 = q[1];
                union { uint4 u; bf16x8 h; } cv;
                cv.u.x = pack_bf16x2(a.x, a.y);
                cv.u.y = pack_bf16x2(a.z, a.w);
                cv.u.z = pack_bf16x2(c4.x, c4.y);
                cv.u.w = pack_bf16x2(c4.z, c4.w);
                bq[kc] = cv.h;
            }
        }
        __syncthreads();   // smT ready; all waves past corr(s-1) -> smT safe,
                           // and past merge(s-1) -> smC free

        // ---- 2. corr: 48 groups = 4 cm x 12 pixel-tiles over 8 waves x 6 ----
        {
            const unsigned* smTd = (const unsigned*)smT;
#pragma unroll 1
            for (int i = 0; i < 6; ++i) {
                const int g  = wave * 6 + i;          // 0..47
                const int j  = g / 12;                // cm_local 0..3
                const int tl = g - 12 * j;            // pixel tile 0..11
                const int p  = (tl << 4) + n;         // flat halo pixel 0..191
                const int pc = p < 180 ? p : 179;     // clamp tail (no store)
                const int py = pc / 18;
                const int px = pc - 18 * py;
                const int pl = px & 1;                // parity plane select
                // dword base: [j][pl][row=py+qh][((px-pl)/2) + jq*4]
                const int base = ((j * 2 + pl) * 25 + py + qh) * 17
                               + ((px - pl) >> 1) + (jq << 2);
                f32x4 a4a = (f32x4){0.f, 0.f, 0.f, 0.f};
                f32x4 a4b = (f32x4){0.f, 0.f, 0.f, 0.f};
#pragma unroll
                for (int kc = 0; kc < 8; ++kc) {
                    const int d = base + kc * 34;     // +2 rows per kc
                    union { uint4 u; bf16x8 h; } fr;
                    fr.u.x = smTd[d];     fr.u.y = smTd[d + 1];
                    fr.u.z = smTd[d + 2]; fr.u.w = smTd[d + 3];
                    if (kc & 1)
                        a4b = __builtin_amdgcn_mfma_f32_16x16x32_bf16(
                            bq[kc], fr.h, a4b, 0, 0, 0);
                    else
                        a4a = __builtin_amdgcn_mfma_f32_16x16x32_bf16(
                            bq[kc], fr.h, a4a, 0, 0, 0);
                }
                f32x4 a4 = a4a + a4b;
                // D[row=quad*4+r = ct][col=n = pixel]; slab-ch = j*16+quad*4+r
                const int gy = y0 - 1 + py, gx = x0 - 1 + px;
                const bool valid = ((unsigned)gy < 128u) && ((unsigned)gx < 128u);
                uint2 v;
                v.x = valid ? pack_bf16x2(a4[0], a4[1]) : 0u;  // SAME-pad zero
                v.y = valid ? pack_bf16x2(a4[2], a4[3]) : 0u;
                if (p < 180)
                    *(uint2*)&smC[p * 72 + (j << 4) + (quad << 2)] = v;
            }
        }
        __syncthreads();   // smC ready; smT free for next slab's staging

        // ---- 3. merge on slab channels c0 = 64s (r5-verbatim scheme) ----
        {
            const unsigned short* wpb = Wb + (size_t)n * 256 + (s << 6) + (quad << 3);
            bf16x8 afc[4];
#pragma unroll
            for (int ct = 0; ct < 4; ++ct)
                afc[ct] = *(const bf16x8*)(wpb + (size_t)ct * 4096);
#pragma unroll 1
            for (int idx = 0; idx < 18; ++idx) {
                const int nidx = idx < 17 ? idx + 1 : 17;
                const int nkk = nidx >> 1, nkc = nidx & 1;
                bf16x8 afn[4];
#pragma unroll
                for (int ct = 0; ct < 4; ++ct)
                    afn[ct] = *(const bf16x8*)(wpb + (size_t)nkk * 16384
                                                   + (nkc << 5) + (size_t)ct * 4096);
                const int kk = idx >> 1, kc = idx & 1;
                const int dy = kk / 3, dx = kk - 3 * dy;
                const int prow = wave + dy;            // wave = out row, 0..9
                const int pcol = n + dx;               // 0..17
                bf16x8 bf = *(const bf16x8*)&smC[(prow * 18 + pcol) * 72
                                                 + (kc << 5) + (quad << 3)];
#pragma unroll
                for (int ct = 0; ct < 4; ++ct)
                    acc[ct] = __builtin_amdgcn_mfma_f32_16x16x32_bf16(
                        afc[ct], bf, acc[ct], 0, 0, 0);
#pragma unroll
                for (int ct = 0; ct < 4; ++ct) afc[ct] = afn[ct];
            }
        }
        // next slab: staging writes smT only after corr(s) readers passed the
        // post-corr barrier; merge(s) doesn't touch smT -> 2 barriers/slab OK
    }

    // ---- epilogue: D[row=quad*4+r = co][col=n], + bias, fp32 out ----
#pragma unroll
    for (int ct = 0; ct < 4; ++ct) {
        const int y   = y0 + wave;
        const int x   = x0 + n;
        const int co0 = (ct << 4) + (quad << 2);
        float* op = out + (((size_t)((b << 6) + co0) << 7) + y) * 128 + x;
#pragma unroll
        for (int r = 0; r < 4; ++r)
            op[(size_t)r << 14] = acc[ct][r] + bias[co0 + r];
    }
}

extern "C" void kernel_launch(void* const* d_in, const int* in_sizes, int n_in,
                              void* d_out, int out_size, void* d_ws, size_t ws_size,
                              hipStream_t stream)
{
    const float* tp   = (const float*)d_in[0];   // template [8,16,16,16]
    const float* tm   = (const float*)d_in[1];   // tomatch  [8,16,128,128]
    const float* Wt   = (const float*)d_in[2];   // W        [64,256,3,3]
    const float* bias = (const float*)d_in[3];   // b        [64]
    float* out = (float*)d_out;                  // [8,64,128,128] fp32

    unsigned short* Wb = (unsigned short*)d_ws;  // 294 KB

    wt_kernel<<<dim3(576), dim3(256), 0, stream>>>(Wt, Wb);
    fused_mfma<<<dim3(8, 16, 8), dim3(512), 0, stream>>>(tp, tm, Wb, bias, out);
}

// Round 6
// 400.118 us; speedup vs baseline: 1.2510x; 1.2510x over previous
//
#include <hip/hip_runtime.h>
#include <hip/hip_bf16.h>

// ---------------------------------------------------------------------------
// DenseCorr2d_full — FUSED corr+merge on MFMA bf16 (round 9).
//
// = round-8 geometry (64co x 8y x 16x tile, grid 1024, LDS 39.9KB -> 4
//   blocks/CU fit) with the ONE fix: __launch_bounds__(512,4) instead of
//   (512,8). r8's (512,8) forced a 64-VGPR budget the live set couldn't
//   meet -> allocator collapsed to VGPR_Count=32 with massive scratch
//   (WRITE_SIZE 32.8->192.5MB, 450MB/dispatch spill traffic, 453µs).
//   This code family compiles at 60-64 VGPR naturally under (512,4);
//   at <=64 VGPR the HW itself allows 8 waves/SIMD, so the 4-blocks/CU
//   occupancy comes from the small LDS footprint, not from the bound.
// ws layout: Wb bf16 [9][64][256] only.
// ---------------------------------------------------------------------------

typedef __attribute__((ext_vector_type(4))) float  f32x4;
typedef __attribute__((ext_vector_type(8))) short  bf16x8;

__device__ inline unsigned int pack_bf16x2(float a, float b) {
    unsigned int ua = __builtin_bit_cast(unsigned int, a);
    unsigned int ub = __builtin_bit_cast(unsigned int, b);
    ua = (ua + 0x7fffu + ((ua >> 16) & 1u)) >> 16;   // RNE
    ub = (ub + 0x7fffu + ((ub >> 16) & 1u)) >> 16;
    return ua | (ub << 16);
}
__device__ inline unsigned short cvt1(float f) {
    unsigned int u = __builtin_bit_cast(unsigned int, f);
    return (unsigned short)((u + 0x7fffu + ((u >> 16) & 1u)) >> 16);
}

// ---------------- W transform: [co][cin][3][3] fp32 -> Wb[kk][co][256] bf16 -
__global__ __launch_bounds__(256) void wt_kernel(
    const float* __restrict__ W, unsigned short* __restrict__ Wb)
{
    int idx = (int)blockIdx.x * 256 + (int)threadIdx.x;   // < 9*64*256
    int c  = idx & 255;
    int rem = idx >> 8;
    int co = rem % 64;
    int kk = rem / 64;
    Wb[idx] = cvt1(W[(size_t)co * 2304 + (size_t)c * 9 + kk]);
}

// ---------------- Fused corr + 3x3 SAME merge conv --------------------------
__global__ __launch_bounds__(512, 4) void fused_mfma(
    const float* __restrict__ tp, const float* __restrict__ tm,
    const unsigned short* __restrict__ Wb, const float* __restrict__ bias,
    float* __restrict__ out)
{
    // tm halo, 2 parity copies: [cm 4][par 2][row 25][pitch 34] = 13600 B
    // (pitch 17 dwords, odd -> n-lanes spread banks like r5's pitch 41)
    __shared__ __align__(16) unsigned short smT[4 * 2 * 25 * 34];
    // corr slab: [pix 180 = 10r x 18c][72 ch-pitch] = 25920 B
    __shared__ __align__(16) unsigned short smC[180 * 72];

    const int t    = threadIdx.x;
    const int wave = t >> 6, lane = t & 63;
    const int n    = lane & 15, quad = lane >> 4;
    const int qh   = quad >> 1, jq = quad & 1;

    const int x0 = (int)blockIdx.x << 4;   // 0..112
    const int y0 = (int)blockIdx.y << 3;   // 0..120
    const int b  = (int)blockIdx.z;

    f32x4 acc[4];                          // merge accumulators [ct]
#pragma unroll
    for (int a = 0; a < 4; ++a) acc[a] = (f32x4){0.f, 0.f, 0.f, 0.f};

#pragma unroll 1
    for (int s = 0; s < 4; ++s) {
        // ---- 1. stage tm halo for cm = 4s..4s+3: rows y0-1..y0+23,
        //         cols x0-1..x0+31 (edge-clamped), parity-shifted copy ----
        {
            const float* tmb = tm + ((size_t)(b * 16 + (s << 2)) << 14);
#pragma unroll 1
            for (int e = t; e < 3400; e += 512) {     // 4 cm * 25 r * 34 c
                int cm  = e / 850;
                int rem = e - 850 * cm;
                int r   = rem / 34;
                int c   = rem - 34 * r;
                int gy = y0 - 1 + r; gy = gy < 0 ? 0 : (gy > 127 ? 127 : gy);
                int gx = x0 - 1 + c; gx = gx < 0 ? 0 : (gx > 127 ? 127 : gx);
                unsigned short h = cvt1(tmb[((size_t)cm << 14) + (gy << 7) + gx]);
                int a0 = cm * 1700 + r * 34 + c;      // parity-0 plane
                smT[a0] = h;                          // copy1[c-1] = tm[c]
                if (c > 0) smT[a0 + 849] = h;         // +850 plane, -1 col
            }
        }

        // ---- corr A-frags (reloaded per slab; asm defeats LICM so the 32
        //      regs don't stay live across merge). L1-hot after slab 0. ----
        bf16x8 bq[8];
        {
            const float* tpb = tp + (((size_t)(b * 16 + n)) << 8);
            asm volatile("" : "+v"(tpb));
#pragma unroll
            for (int kc = 0; kc < 8; ++kc) {
                const float4* q = (const float4*)(tpb + (((2 * kc + qh) << 4) + (jq << 3)));
                float4 a = q[0], c4 = q[1];
                union { uint4 u; bf16x8 h; } cv;
                cv.u.x = pack_bf16x2(a.x, a.y);
                cv.u.y = pack_bf16x2(a.z, a.w);
                cv.u.z = pack_bf16x2(c4.x, c4.y);
                cv.u.w = pack_bf16x2(c4.z, c4.w);
                bq[kc] = cv.h;
            }
        }
        __syncthreads();   // smT ready; all waves past corr(s-1) -> smT safe,
                           // and past merge(s-1) -> smC free

        // ---- 2. corr: 48 groups = 4 cm x 12 pixel-tiles over 8 waves x 6 ----
        {
            const unsigned* smTd = (const unsigned*)smT;
#pragma unroll 1
            for (int i = 0; i < 6; ++i) {
                const int g  = wave * 6 + i;          // 0..47
                const int j  = g / 12;                // cm_local 0..3
                const int tl = g - 12 * j;            // pixel tile 0..11
                const int p  = (tl << 4) + n;         // flat halo pixel 0..191
                const int pc = p < 180 ? p : 179;     // clamp tail (no store)
                const int py = pc / 18;
                const int px = pc - 18 * py;
                const int pl = px & 1;                // parity plane select
                // dword base: [j][pl][row=py+qh][((px-pl)/2) + jq*4]
                const int base = ((j * 2 + pl) * 25 + py + qh) * 17
                               + ((px - pl) >> 1) + (jq << 2);
                f32x4 a4a = (f32x4){0.f, 0.f, 0.f, 0.f};
                f32x4 a4b = (f32x4){0.f, 0.f, 0.f, 0.f};
#pragma unroll
                for (int kc = 0; kc < 8; ++kc) {
                    const int d = base + kc * 34;     // +2 rows per kc
                    union { uint4 u; bf16x8 h; } fr;
                    fr.u.x = smTd[d];     fr.u.y = smTd[d + 1];
                    fr.u.z = smTd[d + 2]; fr.u.w = smTd[d + 3];
                    if (kc & 1)
                        a4b = __builtin_amdgcn_mfma_f32_16x16x32_bf16(
                            bq[kc], fr.h, a4b, 0, 0, 0);
                    else
                        a4a = __builtin_amdgcn_mfma_f32_16x16x32_bf16(
                            bq[kc], fr.h, a4a, 0, 0, 0);
                }
                f32x4 a4 = a4a + a4b;
                // D[row=quad*4+r = ct][col=n = pixel]; slab-ch = j*16+quad*4+r
                const int gy = y0 - 1 + py, gx = x0 - 1 + px;
                const bool valid = ((unsigned)gy < 128u) && ((unsigned)gx < 128u);
                uint2 v;
                v.x = valid ? pack_bf16x2(a4[0], a4[1]) : 0u;  // SAME-pad zero
                v.y = valid ? pack_bf16x2(a4[2], a4[3]) : 0u;
                if (p < 180)
                    *(uint2*)&smC[p * 72 + (j << 4) + (quad << 2)] = v;
            }
        }
        __syncthreads();   // smC ready; smT free for next slab's staging

        // ---- 3. merge on slab channels c0 = 64s (r5-verbatim scheme) ----
        {
            const unsigned short* wpb = Wb + (size_t)n * 256 + (s << 6) + (quad << 3);
            bf16x8 afc[4];
#pragma unroll
            for (int ct = 0; ct < 4; ++ct)
                afc[ct] = *(const bf16x8*)(wpb + (size_t)ct * 4096);
#pragma unroll 1
            for (int idx = 0; idx < 18; ++idx) {
                const int nidx = idx < 17 ? idx + 1 : 17;
                const int nkk = nidx >> 1, nkc = nidx & 1;
                bf16x8 afn[4];
#pragma unroll
                for (int ct = 0; ct < 4; ++ct)
                    afn[ct] = *(const bf16x8*)(wpb + (size_t)nkk * 16384
                                                   + (nkc << 5) + (size_t)ct * 4096);
                const int kk = idx >> 1, kc = idx & 1;
                const int dy = kk / 3, dx = kk - 3 * dy;
                const int prow = wave + dy;            // wave = out row, 0..9
                const int pcol = n + dx;               // 0..17
                bf16x8 bf = *(const bf16x8*)&smC[(prow * 18 + pcol) * 72
                                                 + (kc << 5) + (quad << 3)];
#pragma unroll
                for (int ct = 0; ct < 4; ++ct)
                    acc[ct] = __builtin_amdgcn_mfma_f32_16x16x32_bf16(
                        afc[ct], bf, acc[ct], 0, 0, 0);
#pragma unroll
                for (int ct = 0; ct < 4; ++ct) afc[ct] = afn[ct];
            }
        }
        // next slab: staging writes smT only after corr(s) readers passed the
        // post-corr barrier; merge(s) doesn't touch smT -> 2 barriers/slab OK
    }

    // ---- epilogue: D[row=quad*4+r = co][col=n], + bias, fp32 out ----
#pragma unroll
    for (int ct = 0; ct < 4; ++ct) {
        const int y   = y0 + wave;
        const int x   = x0 + n;
        const int co0 = (ct << 4) + (quad << 2);
        float* op = out + (((size_t)((b << 6) + co0) << 7) + y) * 128 + x;
#pragma unroll
        for (int r = 0; r < 4; ++r)
            op[(size_t)r << 14] = acc[ct][r] + bias[co0 + r];
    }
}

extern "C" void kernel_launch(void* const* d_in, const int* in_sizes, int n_in,
                              void* d_out, int out_size, void* d_ws, size_t ws_size,
                              hipStream_t stream)
{
    const float* tp   = (const float*)d_in[0];   // template [8,16,16,16]
    const float* tm   = (const float*)d_in[1];   // tomatch  [8,16,128,128]
    const float* Wt   = (const float*)d_in[2];   // W        [64,256,3,3]
    const float* bias = (const float*)d_in[3];   // b        [64]
    float* out = (float*)d_out;                  // [8,64,128,128] fp32

    unsigned short* Wb = (unsigned short*)d_ws;  // 294 KB

    wt_kernel<<<dim3(576), dim3(256), 0, stream>>>(Wt, Wb);
    fused_mfma<<<dim3(8, 16, 8), dim3(512), 0, stream>>>(tp, tm, Wb, bias, out);
}